// Round 7
// baseline (1671.835 us; speedup 1.0000x reference)
//
#include <hip/hip_runtime.h>

// SwitchGNN pipeline (tile-bucket edition):
//  out = (1/7) * sum_t [ (segsum_t(x[src]) / max(cnt,1)) @ W_t + 1{cnt>0} b_t ]
// P0 convx_k: x -> bf16 rows (256B each); halves gather payload
// P1 wconv_k: W -> bf16, transposed [t][f][k], XOR-swizzled (GEMM B operand)
// P2 fill2_k: append edges to per-(type, 128-node-tile) buckets: sequential
//             writes (no 64B-line waste; was 109MB -> ~14MB), padded counters
// P3 agg2_k : per tile-block: LDS fp32 accumulator; per edge 2x128B coalesced
//             ushort gathers + 2 LDS atomicAdd (bank=lane%32 -> 2-way, free);
//             exact counts in LDS; scale+bf16+swizzle -> aggb chunk, cnti
// P4 gemm_k : 128-row tiles, 8 waves, K=7x128, global_load_lds(16B),
//             mfma_f32_16x16x32_bf16, bias+mean epilogue.

constexpr int NN = 100000;
constexpr int NT = 7;
constexpr int NE = 250000;
constexpr int DD = 128;
constexpr int NTILE_F = (NN + 127) / 128;   // 782 tiles
constexpr int NROWS = NTILE_F * 128;        // 100096 padded rows
constexpr int CAPB = 512;                   // bucket cap; Binomial mean 320, ~10.7 sigma
constexpr int LSTR = 130;                   // LDS agg row stride (dwords), +2 pad

typedef short bf16x8 __attribute__((ext_vector_type(8)));
typedef float f32x4 __attribute__((ext_vector_type(4)));

__device__ __forceinline__ unsigned pack_bf16x2(float lo, float hi) {
    unsigned a = __float_as_uint(lo), b = __float_as_uint(hi);
    unsigned al = (a + 0x7FFFu + ((a >> 16) & 1u)) >> 16;          // RNE
    unsigned bh = (b + 0x7FFFu + ((b >> 16) & 1u)) & 0xFFFF0000u;
    return al | bh;
}

// ---------------------------------------------------------------- conv x ----
__global__ __launch_bounds__(256) void convx_k(
    const float* __restrict__ x, uint4* __restrict__ xb)
{
    int id = blockIdx.x * 256 + threadIdx.x;
    const float4* src = (const float4*)x;
    float4 v0 = src[(size_t)id * 2];
    float4 v1 = src[(size_t)id * 2 + 1];
    uint4 o;
    o.x = pack_bf16x2(v0.x, v0.y);
    o.y = pack_bf16x2(v0.z, v0.w);
    o.z = pack_bf16x2(v1.x, v1.y);
    o.w = pack_bf16x2(v1.z, v1.w);
    xb[id] = o;
}

// ---------------------------------------------------------------- W conv ----
// WTb[t][f][k] bf16, row=256B, granule ^= f&7. One wave per (t,f).
__global__ __launch_bounds__(256) void wconv_k(
    const float* __restrict__ W, char* __restrict__ WTb)
{
    int wid = (blockIdx.x * 256 + threadIdx.x) >> 6;
    int lane = threadIdx.x & 63;
    int t = wid >> 7, f = wid & 127;
    if (t >= NT) return;
    const float* Wt = W + (size_t)t * DD * DD;
    float w0 = Wt[(size_t)(2 * lane) * DD + f];
    float w1 = Wt[(size_t)(2 * lane + 1) * DD + f];
    int gran = (lane >> 2) ^ (f & 7);
    *(unsigned*)(WTb + (size_t)t * 32768 + f * 256 + gran * 16 + (lane & 3) * 4)
        = pack_bf16x2(w0, w1);
}

// ------------------------------------------------------------------ fill ----
// Append edge to bucket (t, dst>>7). Counters padded to 64B lines.
__global__ __launch_bounds__(256) void fill2_k(
    const int* __restrict__ ei,      // [NT][2][NE]
    int* __restrict__ bcnt,          // [NT*NTILE_F][16] padded counters, zeroed
    int* __restrict__ bedge)         // [NT*NTILE_F][CAPB]
{
    int e = (blockIdx.x * 256 + threadIdx.x) * 2;
    int t = blockIdx.y;
    if (e >= NE) return;
    const int* p = ei + (size_t)t * 2 * NE;
    int2 s2 = *(const int2*)(p + e);
    int2 d2 = *(const int2*)(p + NE + e);
    #pragma unroll
    for (int k = 0; k < 2; ++k) {
        int src = k ? s2.y : s2.x;
        int dst = k ? d2.y : d2.x;
        int bkt = t * NTILE_F + (dst >> 7);
        int val = src | ((dst & 127) << 17);          // src < 2^17
        int pos = atomicAdd(bcnt + (size_t)bkt * 16, 1);
        if (pos < CAPB) bedge[(size_t)bkt * CAPB + pos] = val;
    }
}

// ------------------------------------------------------------- aggregate ----
// One block per 128-node tile (512 thr, 8 waves). Per type: zero LDS acc,
// stream bucket edges (one edge per wave-iteration: lane l accumulates
// features l and l+64), then scale+pack+swizzle to aggb and write cnti.
__global__ __launch_bounds__(512) void agg2_k(
    const unsigned short* __restrict__ x16,  // xb viewed as [NN][128] bf16
    const int* __restrict__ bcnt,
    const int* __restrict__ bedge,
    char* __restrict__ aggb,         // [NT][nc][256B] chunk, swizzled
    int* __restrict__ cnti,          // [NN][NT]
    int c0, int nc)
{
    __shared__ float aggf[128 * LSTR];   // 66.6 KB
    __shared__ int cntr[128];
    int tid = threadIdx.x;
    int lane = tid & 63, w = tid >> 6;
    int tileg = (c0 >> 7) + blockIdx.x;
    int node0 = tileg << 7;
    const size_t tstride = (size_t)nc * 256;

    for (int t = 0; t < NT; ++t) {
        __syncthreads();   // previous type's scale-phase reads done
        #pragma unroll
        for (int k = 0; k < 9; ++k) {                 // zero 4160 float4s
            int idx = tid + k * 512;
            if (idx < (128 * LSTR) / 4) ((f32x4*)aggf)[idx] = (f32x4)0.0f;
        }
        if (tid < 128) cntr[tid] = 0;
        __syncthreads();

        int bkt = t * NTILE_F + tileg;
        int nE = bcnt[(size_t)bkt * 16];
        if (nE > CAPB) nE = CAPB;
        const int* eb = bedge + (size_t)bkt * CAPB;

        #pragma unroll 4
        for (int i = w; i < nE; i += 8) {
            unsigned val = (unsigned)eb[i];           // broadcast load
            int src = val & 0x1FFFF;
            int r = val >> 17;
            if (lane == 0) atomicAdd(&cntr[r], 1);
            unsigned u0 = x16[(size_t)src * 128 + lane];        // 128B coalesced
            unsigned u1 = x16[(size_t)src * 128 + 64 + lane];   // 128B coalesced
            atomicAdd(&aggf[r * LSTR + lane], __uint_as_float(u0 << 16));
            atomicAdd(&aggf[r * LSTR + 64 + lane], __uint_as_float(u1 << 16));
        }
        __syncthreads();

        // scale + bf16 pack + swizzle -> aggb; exact counts -> cnti
        int r = tid >> 2, h = tid & 3;                // 128 rows x 4 quarters
        int c = cntr[r];
        float s = 1.0f / fmaxf((float)c, 1.0f);       // mean folded pre-GEMM
        char* obase = aggb + (size_t)t * tstride
                    + ((size_t)blockIdx.x * 128 + r) * 256;
        #pragma unroll
        for (int j = 0; j < 16; ++j) {
            int d = h * 16 + j;                       // dword index 0..63
            unsigned pk = pack_bf16x2(aggf[r * LSTR + 2 * d] * s,
                                      aggf[r * LSTR + 2 * d + 1] * s);
            *(unsigned*)(obase + (((d >> 2) ^ (r & 7)) << 4) + (d & 3) * 4) = pk;
        }
        int node = node0 + r;
        if (h == 0 && node < NN) cnti[(size_t)node * NT + t] = c;
    }
}

// ------------------------------------------------------------------ gemm ----
// 512 threads = 8 waves; wave w=(wy,wx): rows wy*32..+31, cols wx*64..+63.
// K-loop over 7 types (K=896, BK=128). Rows are chunk-local.
__global__ __launch_bounds__(512) void gemm_k(
    const char* __restrict__ aggb, const char* __restrict__ WTb,
    const int* __restrict__ cnt, const float* __restrict__ bias,
    float* __restrict__ out, int c0, int nc)
{
    __shared__ char sA[128 * 256];   // 32 KB
    __shared__ char sW[128 * 256];   // 32 KB
    int tid = threadIdx.x;
    int w = tid >> 6, lane = tid & 63;
    int wy = w >> 1, wx = w & 1;
    int n0 = c0 + blockIdx.x * 128;
    const size_t tstride = (size_t)nc * 256;

    f32x4 acc[2][4];
    #pragma unroll
    for (int i = 0; i < 2; ++i)
        #pragma unroll
        for (int j = 0; j < 4; ++j) acc[i][j] = (f32x4)0.0f;

    for (int t = 0; t < NT; ++t) {
        __syncthreads();   // prev MFMA readers done before restage
        const char* asrc = aggb + (size_t)t * tstride + (size_t)blockIdx.x * 32768;
        const char* wsrc = WTb + (size_t)t * 32768;
        #pragma unroll
        for (int i = 0; i < 4; ++i) {
            int ch = w * 4 + i;     // 32 chunks x 1KB each
            __builtin_amdgcn_global_load_lds(
                (const __attribute__((address_space(1))) void*)(asrc + ch * 1024 + lane * 16),
                (__attribute__((address_space(3))) void*)(sA + ch * 1024), 16, 0, 0);
            __builtin_amdgcn_global_load_lds(
                (const __attribute__((address_space(1))) void*)(wsrc + ch * 1024 + lane * 16),
                (__attribute__((address_space(3))) void*)(sW + ch * 1024), 16, 0, 0);
        }
        __syncthreads();   // compiler drains vmcnt before barrier

        #pragma unroll
        for (int c = 0; c < 4; ++c) {
            int gsel = ((c * 4 + (lane >> 4)) ^ (lane & 7)) << 4;
            bf16x8 A0 = *(const bf16x8*)(sA + (wy * 32 + (lane & 15)) * 256 + gsel);
            bf16x8 A1 = *(const bf16x8*)(sA + (wy * 32 + 16 + (lane & 15)) * 256 + gsel);
            #pragma unroll
            for (int nj = 0; nj < 4; ++nj) {
                bf16x8 B = *(const bf16x8*)(sW + (wx * 64 + nj * 16 + (lane & 15)) * 256 + gsel);
                acc[0][nj] = __builtin_amdgcn_mfma_f32_16x16x32_bf16(A0, B, acc[0][nj], 0, 0, 0);
                acc[1][nj] = __builtin_amdgcn_mfma_f32_16x16x32_bf16(A1, B, acc[1][nj], 0, 0, 0);
            }
        }
    }

    // epilogue: mean over types + per-type bias where cnt>0
    const float inv7 = 1.0f / (float)NT;
    #pragma unroll
    for (int mi = 0; mi < 2; ++mi) {
        #pragma unroll
        for (int v = 0; v < 4; ++v) {
            int n = n0 + wy * 32 + mi * 16 + (lane >> 4) * 4 + v;
            if (n >= NN) continue;
            float add[4] = {0.f, 0.f, 0.f, 0.f};
            for (int t = 0; t < NT; ++t) {
                if (cnt[(size_t)n * NT + t] > 0) {
                    #pragma unroll
                    for (int nj = 0; nj < 4; ++nj)
                        add[nj] += bias[(size_t)t * DD + wx * 64 + nj * 16 + (lane & 15)];
                }
            }
            #pragma unroll
            for (int nj = 0; nj < 4; ++nj)
                out[(size_t)n * DD + wx * 64 + nj * 16 + (lane & 15)]
                    = inv7 * (acc[mi][nj][v] + add[nj]);
        }
    }
}

// ---------------------------------------------------------------- launch ----
extern "C" void kernel_launch(void* const* d_in, const int* in_sizes, int n_in,
                              void* d_out, int out_size, void* d_ws, size_t ws_size,
                              hipStream_t stream) {
    const float* x  = (const float*)d_in[0];
    const int*   ei = (const int*)d_in[1];
    const float* W  = (const float*)d_in[2];
    const float* b  = (const float*)d_in[3];
    float* out = (float*)d_out;
    char* ws = (char*)d_ws;

    // fixed tables: ~40.2 MB (R4/R6 proved >= ~118 MB ws available)
    size_t off = 0;
    char* xb    = ws + off; off += (size_t)NN * 256;                     // 25.6 MB
    char* WTb   = ws + off; off += (size_t)NT * 128 * 256;               // 224 KB
    int*  bcnt  = (int*)(ws + off); off += (size_t)NT * NTILE_F * 16 * 4;// 350 KB
    int*  bedge = (int*)(ws + off); off += (size_t)NT * NTILE_F * CAPB * 4; // 11.2 MB
    int*  cnti  = (int*)(ws + off); off += (size_t)NN * NT * 4;          //  2.8 MB
    char* aggb  = ws + off;                                              // remainder

    // chunk size: as many 128-row tiles as fit in the remaining workspace
    size_t avail = (ws_size > off) ? (ws_size - off) : 0;
    int Nc = (int)(avail / ((size_t)NT * 256));
    Nc &= ~127;
    if (Nc < 128) Nc = 128;
    if (Nc > NROWS) Nc = NROWS;

    convx_k<<<(NN * DD / 8 + 255) / 256, 256, 0, stream>>>(x, (uint4*)xb);
    wconv_k<<<(NT * 128 + 3) / 4, 256, 0, stream>>>(W, WTb);
    hipMemsetAsync(bcnt, 0, (size_t)NT * NTILE_F * 16 * 4, stream);
    fill2_k<<<dim3((NE / 2 + 255) / 256, NT), 256, 0, stream>>>(ei, bcnt, bedge);

    for (int c0 = 0; c0 < NN; c0 += Nc) {
        int nc = (NROWS - c0 < Nc) ? (NROWS - c0) : Nc;   // multiple of 128
        agg2_k<<<nc / 128, 512, 0, stream>>>(
            (const unsigned short*)xb, bcnt, bedge, aggb, cnti, c0, nc);
        gemm_k<<<nc / 128, 512, 0, stream>>>(aggb, WTb, cnti, b, out, c0, nc);
    }
}

// Round 8
// 299.991 us; speedup vs baseline: 5.5730x; 5.5730x over previous
//
#include <hip/hip_runtime.h>

// SwitchGNN split pipeline (R6 structure + XCD-partitioned fill):
//  out = (1/7) * sum_t [ (segsum_t(x[src]) / max(cnt,1)) @ W_t + 1{cnt>0} b_t ]
// P0 convx_k: x -> bf16 rows (256B each); halves gather payload
// P1 wconv_k: W -> bf16, transposed [t][f][k], XOR-swizzled (GEMM B operand)
// P2 fill_k : bucket edges by (dst,type). XCD-partitioned: blockIdx.x&7 picks
//             a 1/8 dst-range (matches XCD round-robin), so each XCD's bucket
//             writes stay L2-resident -> one writeback per line (was 109MB).
// P3 agg_k  : one wave per node, all 7 types (setup amortized, 2-type
//             interleaved gathers); writes swizzled bf16 rows to aggb chunk
// P4 gemm_k : 128-row tiles, 8 waves, K=7x128, global_load_lds(16B),
//             mfma_f32_16x16x32_bf16, bias+mean epilogue.

constexpr int NN = 100000;
constexpr int NT = 7;
constexpr int NE = 250000;
constexpr int DD = 128;
constexpr int CAP = 20;           // max tracked edges per (n,t); P(Poisson(2.5)>20)~3e-12
constexpr int OVF = CAP - 8;      // overflow slots beyond the 8 fast slots
constexpr int NROWS = ((NN + 127) / 128) * 128;   // 100096 padded rows
constexpr int NPART = 8;                          // dst partitions = XCDs
constexpr int PSIZE = (NN + NPART - 1) / NPART;   // 12500 nodes per partition
constexpr int EPB = 1024;                         // edges per fill block
constexpr int NSLAB = (NE + EPB - 1) / EPB;       // 245 slabs

typedef short bf16x8 __attribute__((ext_vector_type(8)));
typedef float f32x4 __attribute__((ext_vector_type(4)));

__device__ __forceinline__ unsigned pack_bf16x2(float lo, float hi) {
    unsigned a = __float_as_uint(lo), b = __float_as_uint(hi);
    unsigned al = (a + 0x7FFFu + ((a >> 16) & 1u)) >> 16;          // RNE
    unsigned bh = (b + 0x7FFFu + ((b >> 16) & 1u)) & 0xFFFF0000u;
    return al | bh;
}

// ---------------------------------------------------------------- conv x ----
__global__ __launch_bounds__(256) void convx_k(
    const float* __restrict__ x, uint4* __restrict__ xb)
{
    int id = blockIdx.x * 256 + threadIdx.x;
    const float4* src = (const float4*)x;
    float4 v0 = src[(size_t)id * 2];
    float4 v1 = src[(size_t)id * 2 + 1];
    uint4 o;
    o.x = pack_bf16x2(v0.x, v0.y);
    o.y = pack_bf16x2(v0.z, v0.w);
    o.z = pack_bf16x2(v1.x, v1.y);
    o.w = pack_bf16x2(v1.z, v1.w);
    xb[id] = o;
}

// ---------------------------------------------------------------- W conv ----
// WTb[t][f][k] bf16, row=256B, granule ^= f&7. One wave per (t,f).
__global__ __launch_bounds__(256) void wconv_k(
    const float* __restrict__ W, char* __restrict__ WTb)
{
    int wid = (blockIdx.x * 256 + threadIdx.x) >> 6;
    int lane = threadIdx.x & 63;
    int t = wid >> 7, f = wid & 127;
    if (t >= NT) return;
    const float* Wt = W + (size_t)t * DD * DD;
    float w0 = Wt[(size_t)(2 * lane) * DD + f];
    float w1 = Wt[(size_t)(2 * lane + 1) * DD + f];
    int gran = (lane >> 2) ^ (f & 7);
    *(unsigned*)(WTb + (size_t)t * 32768 + f * 256 + gran * 16 + (lane & 3) * 4)
        = pack_bf16x2(w0, w1);
}

// ------------------------------------------------------------------ fill ----
// blockIdx.x = slab*8 + partition. Each block reads its 1024-edge slab and
// keeps only edges whose dst lies in its partition's range, so all bucket
// writes from one XCD hit a 2.8MB L2-resident slice (no line ping-pong).
__global__ __launch_bounds__(256) void fill_k(
    const int* __restrict__ ei,      // [NT][2][NE]
    int* __restrict__ cnt,           // [NN][NT], zeroed
    int* __restrict__ eidx8,         // [NN][NT][8]
    int* __restrict__ ovf)           // [NT][NN][OVF]
{
    int part = blockIdx.x & (NPART - 1);
    int slab = blockIdx.x >> 3;
    int t = blockIdx.y;
    int e0 = slab * EPB + threadIdx.x * 4;
    if (e0 >= NE) return;
    const int* p = ei + (size_t)t * 2 * NE;
    int4 s4 = *(const int4*)(p + e0);        // NE % 4 == 0: in-bounds
    int4 d4 = *(const int4*)(p + NE + e0);
    int lo = part * PSIZE;
    int hi = lo + PSIZE;
    #pragma unroll
    for (int k = 0; k < 4; ++k) {
        int src = k == 0 ? s4.x : k == 1 ? s4.y : k == 2 ? s4.z : s4.w;
        int dst = k == 0 ? d4.x : k == 1 ? d4.y : k == 2 ? d4.z : d4.w;
        if (dst >= lo && dst < hi) {
            int pos = atomicAdd(cnt + (size_t)dst * NT + t, 1);
            if (pos < 8)        eidx8[((size_t)dst * NT + t) * 8 + pos] = src;
            else if (pos < CAP) ovf[((size_t)t * NN + dst) * OVF + (pos - 8)] = src;
        }
    }
}

// ------------------------------------------------------------- aggregate ----
// One wave per row of the chunk (node n = c0 + wid). Lanes 0..6 hold the
// per-type counts, lanes 0..55 the fast-slot indices. Types processed in
// interleaved pairs (2 gather chains in flight). Lane holds features
// 2*lane, 2*lane+1. Rows with n >= NN are written as zeros (never garbage).
__global__ __launch_bounds__(256) void agg_k(
    const char* __restrict__ xb,     // [NN][256B] bf16 rows
    const int* __restrict__ cnt,     // [NN][NT]
    const int* __restrict__ eidx8,   // [NN][NT][8]
    const int* __restrict__ ovf,     // [NT][NN][OVF]
    char* __restrict__ aggb,         // [NT][nc][256B] chunk, swizzled
    int c0, int nc)
{
    int wid = (blockIdx.x * 256 + threadIdx.x) >> 6;
    int lane = threadIdx.x & 63;
    if (wid >= nc) return;
    const int n = c0 + wid;
    const bool live = (n < NN);

    int cntv = (live && lane < NT) ? cnt[(size_t)n * NT + lane] : 0;
    int idxv = (live && lane < 56) ? eidx8[(size_t)n * 56 + lane] : 0;

    int r = wid & 127;
    int gran = (lane >> 2) ^ (r & 7);            // swizzle for ds_read_b128
    char* wbase = aggb + (size_t)(wid >> 7) * 32768 + r * 256
                + gran * 16 + (lane & 3) * 4;
    const size_t tstride = (size_t)nc * 256;

    for (int tp = 0; tp < NT; tp += 2) {
        int cA = __shfl(cntv, tp);
        int cB = (tp + 1 < NT) ? __shfl(cntv, tp + 1) : 0;
        int ccA = cA < CAP ? cA : CAP;
        int ccB = cB < CAP ? cB : CAP;
        int m = ccA > ccB ? ccA : ccB;

        float a0 = 0.f, a1 = 0.f, b0 = 0.f, b1 = 0.f;
        for (int e = 0; e < m; ++e) {            // wave-uniform bounds
            if (e < ccA) {
                int s = (e < 8) ? __shfl(idxv, tp * 8 + e)
                                : ovf[((size_t)tp * NN + n) * OVF + (e - 8)];
                unsigned v = *(const unsigned*)(xb + (size_t)s * 256 + lane * 4);
                a0 += __uint_as_float(v << 16);
                a1 += __uint_as_float(v & 0xFFFF0000u);
            }
            if (e < ccB) {
                int s = (e < 8) ? __shfl(idxv, (tp + 1) * 8 + e)
                                : ovf[((size_t)(tp + 1) * NN + n) * OVF + (e - 8)];
                unsigned v = *(const unsigned*)(xb + (size_t)s * 256 + lane * 4);
                b0 += __uint_as_float(v << 16);
                b1 += __uint_as_float(v & 0xFFFF0000u);
            }
        }
        float sa = 1.0f / fmaxf((float)cA, 1.0f);   // mean folded pre-GEMM
        *(unsigned*)(wbase + (size_t)tp * tstride) = pack_bf16x2(a0 * sa, a1 * sa);
        if (tp + 1 < NT) {
            float sb = 1.0f / fmaxf((float)cB, 1.0f);
            *(unsigned*)(wbase + (size_t)(tp + 1) * tstride) = pack_bf16x2(b0 * sb, b1 * sb);
        }
    }
}

// ------------------------------------------------------------------ gemm ----
// 512 threads = 8 waves; wave w=(wy,wx): rows wy*32..+31, cols wx*64..+63.
// K-loop over 7 types (K=896, BK=128). Rows are chunk-local.
__global__ __launch_bounds__(512) void gemm_k(
    const char* __restrict__ aggb, const char* __restrict__ WTb,
    const int* __restrict__ cnt, const float* __restrict__ bias,
    float* __restrict__ out, int c0, int nc)
{
    __shared__ char sA[128 * 256];   // 32 KB
    __shared__ char sW[128 * 256];   // 32 KB
    int tid = threadIdx.x;
    int w = tid >> 6, lane = tid & 63;
    int wy = w >> 1, wx = w & 1;
    int n0 = c0 + blockIdx.x * 128;
    const size_t tstride = (size_t)nc * 256;

    f32x4 acc[2][4];
    #pragma unroll
    for (int i = 0; i < 2; ++i)
        #pragma unroll
        for (int j = 0; j < 4; ++j) acc[i][j] = (f32x4)0.0f;

    for (int t = 0; t < NT; ++t) {
        __syncthreads();   // prev MFMA readers done before restage
        const char* asrc = aggb + (size_t)t * tstride + (size_t)blockIdx.x * 32768;
        const char* wsrc = WTb + (size_t)t * 32768;
        #pragma unroll
        for (int i = 0; i < 4; ++i) {
            int ch = w * 4 + i;     // 32 chunks x 1KB each
            __builtin_amdgcn_global_load_lds(
                (const __attribute__((address_space(1))) void*)(asrc + ch * 1024 + lane * 16),
                (__attribute__((address_space(3))) void*)(sA + ch * 1024), 16, 0, 0);
            __builtin_amdgcn_global_load_lds(
                (const __attribute__((address_space(1))) void*)(wsrc + ch * 1024 + lane * 16),
                (__attribute__((address_space(3))) void*)(sW + ch * 1024), 16, 0, 0);
        }
        __syncthreads();   // compiler drains vmcnt before barrier

        #pragma unroll
        for (int c = 0; c < 4; ++c) {
            int gsel = ((c * 4 + (lane >> 4)) ^ (lane & 7)) << 4;
            bf16x8 A0 = *(const bf16x8*)(sA + (wy * 32 + (lane & 15)) * 256 + gsel);
            bf16x8 A1 = *(const bf16x8*)(sA + (wy * 32 + 16 + (lane & 15)) * 256 + gsel);
            #pragma unroll
            for (int nj = 0; nj < 4; ++nj) {
                bf16x8 B = *(const bf16x8*)(sW + (wx * 64 + nj * 16 + (lane & 15)) * 256 + gsel);
                acc[0][nj] = __builtin_amdgcn_mfma_f32_16x16x32_bf16(A0, B, acc[0][nj], 0, 0, 0);
                acc[1][nj] = __builtin_amdgcn_mfma_f32_16x16x32_bf16(A1, B, acc[1][nj], 0, 0, 0);
            }
        }
    }

    // epilogue: mean over types + per-type bias where cnt>0
    const float inv7 = 1.0f / (float)NT;
    #pragma unroll
    for (int mi = 0; mi < 2; ++mi) {
        #pragma unroll
        for (int v = 0; v < 4; ++v) {
            int n = n0 + wy * 32 + mi * 16 + (lane >> 4) * 4 + v;
            if (n >= NN) continue;
            float add[4] = {0.f, 0.f, 0.f, 0.f};
            for (int t = 0; t < NT; ++t) {
                if (cnt[(size_t)n * NT + t] > 0) {
                    #pragma unroll
                    for (int nj = 0; nj < 4; ++nj)
                        add[nj] += bias[(size_t)t * DD + wx * 64 + nj * 16 + (lane & 15)];
                }
            }
            #pragma unroll
            for (int nj = 0; nj < 4; ++nj)
                out[(size_t)n * DD + wx * 64 + nj * 16 + (lane & 15)]
                    = inv7 * (acc[mi][nj][v] + add[nj]);
        }
    }
}

// ---------------------------------------------------------------- launch ----
extern "C" void kernel_launch(void* const* d_in, const int* in_sizes, int n_in,
                              void* d_out, int out_size, void* d_ws, size_t ws_size,
                              hipStream_t stream) {
    const float* x  = (const float*)d_in[0];
    const int*   ei = (const int*)d_in[1];
    const float* W  = (const float*)d_in[2];
    const float* b  = (const float*)d_in[3];
    float* out = (float*)d_out;
    char* ws = (char*)d_ws;

    // fixed tables: 84.7 MB (R6 proved this layout + chunked aggb fits ws)
    size_t off = 0;
    char* xb    = ws + off; off += (size_t)NN * 256;                  // 25.6 MB
    char* WTb   = ws + off; off += (size_t)NT * 128 * 256;            // 224 KB
    int*  eidx8 = (int*)(ws + off); off += (size_t)NN * NT * 8 * 4;   // 22.4 MB
    int*  cnti  = (int*)(ws + off); off += (size_t)NN * NT * 4;       //  2.8 MB
    int*  ovfp  = (int*)(ws + off); off += (size_t)NT * NN * OVF * 4; // 33.6 MB
    char* aggb  = ws + off;                                           // remainder

    // chunk size: as many 128-row tiles as fit in the remaining workspace
    size_t avail = (ws_size > off) ? (ws_size - off) : 0;
    int Nc = (int)(avail / ((size_t)NT * 256));
    Nc &= ~127;
    if (Nc < 128) Nc = 128;
    if (Nc > NROWS) Nc = NROWS;

    convx_k<<<(NN * DD / 8 + 255) / 256, 256, 0, stream>>>(x, (uint4*)xb);
    wconv_k<<<(NT * 128 + 3) / 4, 256, 0, stream>>>(W, WTb);
    hipMemsetAsync(cnti, 0, (size_t)NN * NT * 4, stream);
    fill_k<<<dim3(NSLAB * NPART, NT), 256, 0, stream>>>(ei, cnti, eidx8, ovfp);

    for (int c0 = 0; c0 < NN; c0 += Nc) {
        int nc = (NROWS - c0 < Nc) ? (NROWS - c0) : Nc;   // multiple of 128
        agg_k<<<nc / 4, 256, 0, stream>>>(xb, cnti, eidx8, ovfp, aggb, c0, nc);
        gemm_k<<<nc / 128, 512, 0, stream>>>(aggb, WTb, cnti, b, out, c0, nc);
    }
}